// Round 4
// baseline (110.375 us; speedup 1.0000x reference)
//
#include <hip/hip_runtime.h>

// GraphUnetPool: scores = sigmoid(h@w+b); top-k (k=N/2) by exact rank-count;
// new_h = h[idx]*values; un_g = (g@g)[idx][:,idx] via per-row LDS 2-path counting.
// 5 graph nodes: [scores+zero+ones] -> [rank+hist] -> [select+scan] ->
//                [newh+scatter] -> [paths].

typedef unsigned long long u64;
typedef unsigned int u32;

// ---- node1: scores (1 wave/row) + zero rankcnt/deg + edge_attr ones ----
__global__ void fused_scores(const float* __restrict__ h, const float* __restrict__ w,
                             const float* __restrict__ b, u64* __restrict__ keys,
                             int* __restrict__ zerobuf, float4* __restrict__ ones4,
                             int N, int n4) {
    int g = blockIdx.x * blockDim.x + threadIdx.x;
    if (g < 2 * N) zerobuf[g] = 0;              // rankcnt (N) + deg (N), adjacent
    if (g < n4) ones4[g] = make_float4(1.f, 1.f, 1.f, 1.f);
    int wave = g >> 6;
    int lane = threadIdx.x & 63;
    if (wave >= N) return;
    const float4 a = ((const float4*)(h + (size_t)wave * 256))[lane];
    const float4 c = ((const float4*)w)[lane];
    float s = a.x * c.x + a.y * c.y + a.z * c.z + a.w * c.w;
    #pragma unroll
    for (int off = 32; off; off >>= 1) s += __shfl_xor(s, off);
    if (lane == 0) {
        s += b[0];
        float sc = 1.0f / (1.0f + expf(-s));
        u32 sb = __float_as_uint(sc);                       // sc in (0,1): bits monotonic
        keys[wave] = ((u64)sb << 32) | (u32)(~wave);        // ties -> lower index first
    }
}

// ---- node2: rank = #{j: key_j > key_i} (512-key chunks, uniform scalar reads)
//             + out-degree histogram ----
__global__ void rank_hist(const u64* __restrict__ keys, int* __restrict__ rankcnt,
                          const int* __restrict__ ei0, int* __restrict__ deg,
                          int N, int E, int nrank) {
    int b = blockIdx.x, tid = threadIdx.x;
    if (b < nrank) {
        int ngroups = N >> 8;                   // element groups of 256
        int chunk = b / ngroups;                // 512-key chunks
        int elg = b % ngroups;
        int el = (elg << 8) + tid;
        u64 mk = keys[el];
        int base = chunk << 9;
        int cnt = 0;
        #pragma unroll 8
        for (int i = 0; i < 512; ++i) cnt += (keys[base + i] > mk) ? 1 : 0;
        atomicAdd(&rankcnt[el], cnt);
    } else {
        int e0 = ((b - nrank) << 10) + tid;     // 4 edges/thread
        #pragma unroll
        for (int j = 0; j < 4; ++j) {
            int e = e0 + (j << 8);
            if (e < E) atomicAdd(&deg[ei0[e]], 1);
        }
    }
}

// ---- node3: select (rank scatter, outputs idx/batch) + CSR exclusive scan ----
__global__ void select_scan(const u64* __restrict__ keys, const int* __restrict__ rankcnt,
                            const int* __restrict__ batch, int* __restrict__ idx_list,
                            float* __restrict__ val_list, int* __restrict__ rank,
                            float* __restrict__ out_idx, float* __restrict__ out_batch,
                            const int* __restrict__ deg, int* __restrict__ offs,
                            int* __restrict__ cursor, int N, int kN) {
    __shared__ int part[1024];
    int b = blockIdx.x, t = threadIdx.x;
    int nsel = N >> 10;                         // select blocks (1024 thr each)
    if (b < nsel) {
        int i = (b << 10) + t;
        int r = rankcnt[i];
        rank[i] = (r < kN) ? r : kN;            // kN == discard slot
        if (r < kN) {
            idx_list[r] = i;
            val_list[r] = __uint_as_float((u32)(keys[i] >> 32));
            out_idx[r] = (float)i;
            out_batch[r] = (float)batch[i];
        }
    } else {
        // exclusive scan over deg[N], N/1024 elems per thread
        int per = N >> 10;
        int base = t * per;
        int loc[8];
        int s = 0;
        #pragma unroll
        for (int j = 0; j < 8; ++j) { if (j < per) { loc[j] = s; s += deg[base + j]; } }
        part[t] = s;
        __syncthreads();
        for (int d = 1; d < 1024; d <<= 1) {
            int v = (t >= d) ? part[t - d] : 0;
            __syncthreads();
            part[t] += v;
            __syncthreads();
        }
        int excl = (t == 0) ? 0 : part[t - 1];
        #pragma unroll
        for (int j = 0; j < 8; ++j) {
            if (j < per) { int o = excl + loc[j]; offs[base + j] = o; cursor[base + j] = o; }
        }
        if (t == 1023) offs[N] = part[1023];
    }
}

// ---- node4: new_h = h[idx]*values (1 wave/row) + CSR neighbor scatter ----
__global__ void newh_scatter(const float* __restrict__ h, const int* __restrict__ idx_list,
                             const float* __restrict__ val_list, float* __restrict__ out_newh,
                             const int* __restrict__ ei0, const int* __restrict__ ei1,
                             int* __restrict__ cursor, int* __restrict__ nbr,
                             int kN, int E) {
    int b = blockIdx.x, tid = threadIdx.x;
    int nnewh = kN >> 2;                        // 4 waves/block
    if (b < nnewh) {
        int wave = (b << 2) + (tid >> 6);
        int lane = tid & 63;
        int i = idx_list[wave];
        float v = val_list[wave];
        float4 a = ((const float4*)(h + (size_t)i * 256))[lane];
        ((float4*)(out_newh + (size_t)wave * 256))[lane] =
            make_float4(a.x * v, a.y * v, a.z * v, a.w * v);
    } else {
        int e = ((b - nnewh) << 8) + tid;
        if (e < E) {
            int p = atomicAdd(&cursor[ei0[e]], 1);
            nbr[p] = ei1[e];
        }
    }
}

// ---- node5: 2-path accumulation; block per row; 2 first-hop v per wave ----
__global__ void paths_row_kernel(const int* __restrict__ idx_list, const int* __restrict__ offs,
                                 const int* __restrict__ nbr, const int* __restrict__ rank,
                                 float* __restrict__ ung, int kN) {
    extern __shared__ float row[];              // kN+1 floats; row[kN] = discard
    int tid = threadIdx.x;
    for (int i = tid; i < kN + 1; i += 256) row[i] = 0.f;
    __syncthreads();
    int u = idx_list[blockIdx.x];
    int s0 = offs[u], s1 = offs[u + 1];
    int wid = tid >> 6;
    int half = (tid >> 5) & 1;                  // two v's per wave
    int hl = tid & 31;
    for (int p0 = s0 + (wid << 1); p0 < s1; p0 += 8) {
        int p = p0 + half;
        if (p < s1) {
            int v = nbr[p];
            int t0 = offs[v], t1 = offs[v + 1];
            for (int q = t0 + hl; q < t1; q += 32)
                atomicAdd(&row[rank[nbr[q]]], 1.0f);
        }
    }
    __syncthreads();
    float4* dst = (float4*)(ung + (size_t)blockIdx.x * kN);
    const float4* src = (const float4*)row;
    for (int i = tid; i < (kN >> 2); i += 256) dst[i] = src[i];
}

extern "C" void kernel_launch(void* const* d_in, const int* in_sizes, int n_in,
                              void* d_out, int out_size, void* d_ws, size_t ws_size,
                              hipStream_t stream) {
    const float* h = (const float*)d_in[0];
    const int* ei = (const int*)d_in[1];            // [2,E] flat: ei0 = ei, ei1 = ei+E
    const int* batch = (const int*)d_in[3];
    const float* pw = (const float*)d_in[4];
    const float* pb = (const float*)d_in[5];

    int N = in_sizes[3];        // 8192
    int E = in_sizes[1] / 2;    // 262144
    int kN = N / 2;
    if (kN < 2) kN = 2;

    float* out = (float*)d_out;
    float* out_newh = out;                              // kN*256
    float* out_ung = out_newh + (size_t)kN * 256;       // kN*kN
    float* out_ea = out_ung + (size_t)kN * kN;          // E
    float* out_nb = out_ea + E;                         // kN
    float* out_idx = out_nb + kN;                       // kN

    char* ws = (char*)d_ws;
    u64* keys    = (u64*)(ws + 0);          // 64 KB
    int* rankcnt = (int*)(ws + 65536);      // 32 KB \ zeroed together in
    int* deg     = (int*)(ws + 98304);      // 32 KB / fused_scores
    int* idx_list= (int*)(ws + 131072);     // 16 KB
    float* vals  = (float*)(ws + 147456);   // 16 KB
    int* rank    = (int*)(ws + 163840);     // 32 KB
    int* offs    = (int*)(ws + 196608);     // 32 KB + 4
    int* cursor  = (int*)(ws + 229632);     // 32 KB
    int* nbr     = (int*)(ws + 262400);     // 1 MB

    // node1: scores + zero(rankcnt,deg) + ones(edge_attr)
    fused_scores<<<(N * 64 + 255) / 256, 256, 0, stream>>>(h, pw, pb, keys, rankcnt,
                                                           (float4*)out_ea, N, E / 4);
    // node2: rank counting (512-key chunks) + degree histogram
    int nrank = (N >> 9) * (N >> 8);
    int nhist = (E + 1023) / 1024;
    rank_hist<<<nrank + nhist, 256, 0, stream>>>(keys, rankcnt, ei, deg, N, E, nrank);
    // node3: select + scan
    select_scan<<<(N >> 10) + 1, 1024, 0, stream>>>(keys, rankcnt, batch, idx_list, vals,
                                                    rank, out_idx, out_nb, deg, offs,
                                                    cursor, N, kN);
    // node4: new_h + neighbor scatter
    newh_scatter<<<(kN >> 2) + (E >> 8), 256, 0, stream>>>(h, idx_list, vals, out_newh,
                                                           ei, ei + E, cursor, nbr, kN, E);
    // node5: per-row 2-path accumulation
    paths_row_kernel<<<kN, 256, (kN + 1) * 4, stream>>>(idx_list, offs, nbr, rank,
                                                        out_ung, kN);
}

// Round 5
// 97.327 us; speedup vs baseline: 1.1341x; 1.1341x over previous
//
#include <hip/hip_runtime.h>

// GraphUnetPool: scores = sigmoid(h@w+b); top-k (k=N/2) by exact rank-count;
// new_h = h[idx]*values; un_g = (g@g)[idx][:,idx] via per-row LDS 2-path counting.
// 5 graph nodes: [scores+zero+ones] -> [rank+hist] -> [select+scan] ->
//                [newh+scatter+2hop-desc] -> [paths].

typedef unsigned long long u64;
typedef unsigned int u32;

// ---- node1: scores (1 wave/row) + zero rankcnt/deg + edge_attr ones ----
__global__ void fused_scores(const float* __restrict__ h, const float* __restrict__ w,
                             const float* __restrict__ b, u64* __restrict__ keys,
                             int* __restrict__ zerobuf, float4* __restrict__ ones4,
                             int N, int n4) {
    int g = blockIdx.x * blockDim.x + threadIdx.x;
    if (g < 2 * N) zerobuf[g] = 0;              // rankcnt (N) + deg (N), adjacent
    if (g < n4) ones4[g] = make_float4(1.f, 1.f, 1.f, 1.f);
    int wave = g >> 6;
    int lane = threadIdx.x & 63;
    if (wave >= N) return;
    const float4 a = ((const float4*)(h + (size_t)wave * 256))[lane];
    const float4 c = ((const float4*)w)[lane];
    float s = a.x * c.x + a.y * c.y + a.z * c.z + a.w * c.w;
    #pragma unroll
    for (int off = 32; off; off >>= 1) s += __shfl_xor(s, off);
    if (lane == 0) {
        s += b[0];
        float sc = 1.0f / (1.0f + expf(-s));
        u32 sb = __float_as_uint(sc);                       // sc in (0,1): bits monotonic
        keys[wave] = ((u64)sb << 32) | (u32)(~wave);        // ties -> lower index first
    }
}

// ---- node2: rank = #{j: key_j > key_i} (LDS-staged 1024-key tiles) + degree hist ----
__global__ void rank_hist(const u64* __restrict__ keys, int* __restrict__ rankcnt,
                          const int* __restrict__ ei0, int* __restrict__ deg,
                          int N, int E, int nrank) {
    __shared__ u64 lk[1024];
    int b = blockIdx.x, tid = threadIdx.x;
    if (b < nrank) {
        int ngroups = N >> 8;                   // element groups of 256
        int chunk = b / ngroups;                // 1024-key chunks
        int elg = b % ngroups;
        int base = chunk << 10;
        #pragma unroll
        for (int j = 0; j < 4; ++j) lk[tid + (j << 8)] = keys[base + tid + (j << 8)];
        __syncthreads();
        int el = (elg << 8) + tid;
        u64 mk = keys[el];
        int cnt = 0;
        #pragma unroll 16
        for (int i = 0; i < 1024; ++i) cnt += (lk[i] > mk) ? 1 : 0;
        atomicAdd(&rankcnt[el], cnt);
    } else {
        int e0 = ((b - nrank) << 10) + tid;     // 4 edges/thread
        #pragma unroll
        for (int j = 0; j < 4; ++j) {
            int e = e0 + (j << 8);
            if (e < E) atomicAdd(&deg[ei0[e]], 1);
        }
    }
}

// ---- node3: select (rank scatter, outputs idx/batch) + CSR exclusive scan ----
__global__ void select_scan(const u64* __restrict__ keys, const int* __restrict__ rankcnt,
                            const int* __restrict__ batch, int* __restrict__ idx_list,
                            float* __restrict__ val_list, int* __restrict__ rank,
                            float* __restrict__ out_idx, float* __restrict__ out_batch,
                            const int* __restrict__ deg, int* __restrict__ offs,
                            int* __restrict__ cursor, int N, int kN) {
    __shared__ int part[1024];
    int b = blockIdx.x, t = threadIdx.x;
    int nsel = N >> 10;                         // select blocks (1024 thr each)
    if (b < nsel) {
        int i = (b << 10) + t;
        int r = rankcnt[i];
        rank[i] = (r < kN) ? r : kN;            // kN == discard slot
        if (r < kN) {
            idx_list[r] = i;
            val_list[r] = __uint_as_float((u32)(keys[i] >> 32));
            out_idx[r] = (float)i;
            out_batch[r] = (float)batch[i];
        }
    } else {
        // exclusive scan over deg[N], 8 elems per thread (N=8192)
        int per = N >> 10;
        int base = t * per;
        int loc[8];
        int s = 0;
        #pragma unroll
        for (int j = 0; j < 8; ++j) { if (j < per) { loc[j] = s; s += deg[base + j]; } }
        part[t] = s;
        __syncthreads();
        for (int d = 1; d < 1024; d <<= 1) {
            int v = (t >= d) ? part[t - d] : 0;
            __syncthreads();
            part[t] += v;
            __syncthreads();
        }
        int excl = (t == 0) ? 0 : part[t - 1];
        #pragma unroll
        for (int j = 0; j < 8; ++j) {
            if (j < per) { int o = excl + loc[j]; offs[base + j] = o; cursor[base + j] = o; }
        }
        if (t == 1023) offs[N] = part[1023];
    }
}

// ---- node4: new_h = h[idx]*values + scatter with per-slot 2-hop descriptors ----
// Slot p (edge u->v): off2[p]=offs[v], len2[p]=deg[v], nbrrank[p]=rank[v].
__global__ void newh_scatter(const float* __restrict__ h, const int* __restrict__ idx_list,
                             const float* __restrict__ val_list, float* __restrict__ out_newh,
                             const int* __restrict__ ei0, const int* __restrict__ ei1,
                             int* __restrict__ cursor, const int* __restrict__ offs,
                             const int* __restrict__ deg, const int* __restrict__ rank,
                             int* __restrict__ off2, int* __restrict__ len2,
                             int* __restrict__ nbrrank, int kN, int E) {
    int b = blockIdx.x, tid = threadIdx.x;
    int nnewh = kN >> 2;                        // 4 waves/block
    if (b < nnewh) {
        int wave = (b << 2) + (tid >> 6);
        int lane = tid & 63;
        int i = idx_list[wave];
        float v = val_list[wave];
        float4 a = ((const float4*)(h + (size_t)i * 256))[lane];
        ((float4*)(out_newh + (size_t)wave * 256))[lane] =
            make_float4(a.x * v, a.y * v, a.z * v, a.w * v);
    } else {
        int e = ((b - nnewh) << 8) + tid;
        if (e < E) {
            int u = ei0[e], v = ei1[e];
            int p = atomicAdd(&cursor[u], 1);
            off2[p] = offs[v];
            len2[p] = deg[v];
            nbrrank[p] = rank[v];
        }
    }
}

// ---- node5: 2-path accumulation; block per row; flat chains via descriptors ----
__global__ void paths_row_kernel(const int* __restrict__ idx_list, const int* __restrict__ offs,
                                 const int* __restrict__ off2, const int* __restrict__ len2,
                                 const int* __restrict__ nbrrank, float* __restrict__ ung,
                                 int kN) {
    extern __shared__ float row[];              // kN+1 floats; then toff[256], tlen[256]
    int* toff = (int*)(row + kN + 1);
    int* tlen = toff + 256;
    int tid = threadIdx.x;
    for (int i = tid; i < kN + 1; i += 256) row[i] = 0.f;
    __syncthreads();
    int u = idx_list[blockIdx.x];
    int s0 = offs[u], s1 = offs[u + 1];
    int nf = s1 - s0;
    int hw = tid >> 5;                          // half-wave 0..7
    int hl = tid & 31;
    for (int fb = 0; fb < nf; fb += 256) {
        int nt = min(256, nf - fb);
        if (tid < nt) {
            toff[tid] = off2[s0 + fb + tid];    // coalesced descriptor stage
            tlen[tid] = len2[s0 + fb + tid];
        }
        __syncthreads();
        for (int f = hw; f < nt; f += 8) {      // half-wave per first-hop segment
            int t0 = toff[f], L = tlen[f];
            for (int q = hl; q < L; q += 32)
                atomicAdd(&row[nbrrank[t0 + q]], 1.0f);   // 1-deep chain
        }
        __syncthreads();
    }
    float4* dst = (float4*)(ung + (size_t)blockIdx.x * kN);
    const float4* src = (const float4*)row;
    for (int i = tid; i < (kN >> 2); i += 256) dst[i] = src[i];
}

extern "C" void kernel_launch(void* const* d_in, const int* in_sizes, int n_in,
                              void* d_out, int out_size, void* d_ws, size_t ws_size,
                              hipStream_t stream) {
    const float* h = (const float*)d_in[0];
    const int* ei = (const int*)d_in[1];            // [2,E] flat: ei0 = ei, ei1 = ei+E
    const int* batch = (const int*)d_in[3];
    const float* pw = (const float*)d_in[4];
    const float* pb = (const float*)d_in[5];

    int N = in_sizes[3];        // 8192
    int E = in_sizes[1] / 2;    // 262144
    int kN = N / 2;
    if (kN < 2) kN = 2;

    float* out = (float*)d_out;
    float* out_newh = out;                              // kN*256
    float* out_ung = out_newh + (size_t)kN * 256;       // kN*kN
    float* out_ea = out_ung + (size_t)kN * kN;          // E
    float* out_nb = out_ea + E;                         // kN
    float* out_idx = out_nb + kN;                       // kN

    char* ws = (char*)d_ws;
    u64* keys    = (u64*)(ws + 0);          // 64 KB
    int* rankcnt = (int*)(ws + 65536);      // 32 KB \ zeroed together in
    int* deg     = (int*)(ws + 98304);      // 32 KB / fused_scores
    int* idx_list= (int*)(ws + 131072);     // 16 KB
    float* vals  = (float*)(ws + 147456);   // 16 KB
    int* rank    = (int*)(ws + 163840);     // 32 KB
    int* offs    = (int*)(ws + 196608);     // 32 KB + 4
    int* cursor  = (int*)(ws + 229632);     // 32 KB
    int* off2    = (int*)(ws + 262400);     // 1 MB
    int* len2    = (int*)(ws + 1310976);    // 1 MB
    int* nbrrank = (int*)(ws + 2359552);    // 1 MB

    // node1: scores + zero(rankcnt,deg) + ones(edge_attr)
    fused_scores<<<(N * 64 + 255) / 256, 256, 0, stream>>>(h, pw, pb, keys, rankcnt,
                                                           (float4*)out_ea, N, E / 4);
    // node2: rank counting (LDS 1024-key tiles) + degree histogram
    int nrank = (N >> 10) * (N >> 8);
    int nhist = (E + 1023) / 1024;
    rank_hist<<<nrank + nhist, 256, 0, stream>>>(keys, rankcnt, ei, deg, N, E, nrank);
    // node3: select + scan
    select_scan<<<(N >> 10) + 1, 1024, 0, stream>>>(keys, rankcnt, batch, idx_list, vals,
                                                    rank, out_idx, out_nb, deg, offs,
                                                    cursor, N, kN);
    // node4: new_h + scatter with 2-hop descriptors
    newh_scatter<<<(kN >> 2) + (E >> 8), 256, 0, stream>>>(h, idx_list, vals, out_newh,
                                                           ei, ei + E, cursor, offs, deg,
                                                           rank, off2, len2, nbrrank, kN, E);
    // node5: per-row 2-path accumulation
    paths_row_kernel<<<kN, 256, (kN + 1) * 4 + 2048, stream>>>(idx_list, offs, off2, len2,
                                                               nbrrank, out_ung, kN);
}